// Round 6
// baseline (358.027 us; speedup 1.0000x reference)
//
#include <hip/hip_runtime.h>

// Problem constants (fixed by setup_inputs)
#define B_   4
#define H_   128
#define W_   128
#define L_   (H_*W_)        // 16384
#define C_   128
#define N_   8
#define R_   8
#define LS_  4096           // active scan positions per batch (64x64 top-left region)
#define CS_  16             // scan chunk length (steps)
#define NC_  256            // chunks per (b,c) = LS_/CS_
#define ST_  (B_*LS_)       // 16384 total active rows

// ---- workspace layout (in floats) ----
#define OFF_XPROC 0ull
#define OFF_Z     (OFF_XPROC + (size_t)B_*L_*C_)
#define OFF_BANDS (OFF_Z     + (size_t)B_*L_*C_)                 // bands1: [B][3][64][64][C]
#define OFF_U     (OFF_BANDS + (size_t)B_*3*64*64*C_)            // u  [B][4096][C]
#define OFF_DELTA (OFF_U     + (size_t)B_*LS_*C_)
#define OFF_BS    (OFF_DELTA + (size_t)B_*LS_*C_)                // [B][4096][8]
#define OFF_CS    (OFF_BS    + (size_t)B_*LS_*N_)
#define OFF_DSUM  (OFF_CS    + (size_t)B_*LS_*N_)                // [B][NC][C]
#define OFF_HEND  (OFF_DSUM  + (size_t)B_*NC_*C_)                // [B][NC][C][8]
#define OFF_HIN   (OFF_HEND  + (size_t)B_*NC_*C_*N_)
#define OFF_H11   (OFF_HIN   + (size_t)B_*NC_*C_*N_)             // [B][4096][C]
#define OFF_XDBL  (OFF_H11   + (size_t)B_*LS_*C_)                // [ST][32] fp32
#define OFF_WCVT  (OFF_XDBL  + (size_t)ST_*32)                   // ushort region: split weights

typedef __attribute__((ext_vector_type(8))) short bf16x8;
typedef __attribute__((ext_vector_type(4))) float f32x4;

__device__ __forceinline__ float softplus_f(float x) {
    return (x > 20.f) ? x : log1pf(__expf(x));
}

// split fp32 into bf16 hi (round-nearest) + bf16 lo (truncated residual)
__device__ __forceinline__ void split_bf16(float x, short& h, short& l) {
    const unsigned u  = __float_as_uint(x);
    const unsigned hr = (u + 0x7FFFu + ((u >> 16) & 1u)) >> 16;
    h = (short)hr;
    const float hf = __uint_as_float(hr << 16);
    l = (short)(__float_as_uint(x - hf) >> 16);
}

__device__ __forceinline__ f32x4 mfma16(bf16x8 a, bf16x8 b, f32x4 c) {
    return __builtin_amdgcn_mfma_f32_16x16x32_bf16(a, b, c, 0, 0, 0);
}

// ============================================================================
// Weight split: in_proj (256x128), out_proj (128x128), x_proj (24x128 pad 32)
// ============================================================================
__global__ __launch_bounds__(256) void k_cvt(const float* __restrict__ w_in,
        const float* __restrict__ w_out, const float* __restrict__ xw,
        unsigned short* __restrict__ wq) {
    const int i = blockIdx.x * 256 + threadIdx.x;   // 0..53247
    float v; unsigned short *hi, *lo; int idx;
    if (i < 32768)      { v = w_in[i];          hi = wq;         lo = wq + 32768;  idx = i; }
    else if (i < 49152) { v = w_out[i - 32768]; hi = wq + 65536; lo = wq + 81920;  idx = i - 32768; }
    else {
        idx = i - 49152;                         // 0..4095 over [32][128]
        v = (idx < 24*128) ? xw[idx] : 0.f;      // zero-pad rows 24..31
        hi = wq + 98304; lo = wq + 102400;
    }
    short h, l; split_bf16(v, h, l);
    hi[idx] = (unsigned short)h;
    lo[idx] = (unsigned short)l;
}

// ============================================================================
// MFMA split-bf16 GEMM, weights-in-registers, persistent grid-stride.
// (round-4 straight-line body; occupancy raised to 3 waves/SIMD, grid 768)
// out[M x NJ] = in[M x 128] @ w[NJ x 128]^T
//   !EPI: NJ=256, 4 waves side-by-side (wave tile 32x64), chunk = 32 rows.
//   EPI : NJ=128, 2x2 waves, chunk = 64 rows, + bias + resid -> out0.
// Swapped-operand MFMA (W first) => lane's 4 acc regs = 4 consecutive out
// cols of ONE row => float4 stores.
// ============================================================================
template<bool EPI>
__global__ __launch_bounds__(256, 3) void k_gemm2(const float* __restrict__ in,
        const unsigned short* __restrict__ whi, const unsigned short* __restrict__ wlo,
        float* __restrict__ out0, float* __restrict__ out1,
        const float* __restrict__ bias, const float* __restrict__ resid) {
    const int tid  = threadIdx.x;
    const int wave = tid >> 6, lane = tid & 63;
    const int lrow = lane & 15;           // weight-row / A-row lane index
    const int lk8  = (lane >> 4) << 3;    // k-offset within 32-k step
    const int oc4  = (lane >> 4) << 2;    // output-col sub-offset for stores

    int c0, wr;
    if constexpr (EPI) { c0 = (wave & 1) * 64; wr = wave >> 1; }
    else               { c0 = wave * 64;       wr = 0; }

    // ---- preload this wave's B panel (64 cols x K=128, hi+lo) into regs ----
    bf16x8 Bh[4][4], Bl[4][4];
    #pragma unroll
    for (int cb = 0; cb < 4; ++cb)
        #pragma unroll
        for (int ks = 0; ks < 4; ++ks) {
            const size_t boff = (size_t)(c0 + cb * 16 + lrow) * C_ + ks * 32 + lk8;
            Bh[cb][ks] = *(const bf16x8*)(whi + boff);
            Bl[cb][ks] = *(const bf16x8*)(wlo + boff);
        }

    const int nch = EPI ? 1024 : 2048;    // chunks of (EPI?64:32) rows; M=65536
    for (int ch = blockIdx.x; ch < nch; ch += gridDim.x) {
        const int r0 = EPI ? (ch * 64 + wr * 32) : ch * 32;
        f32x4 acc[2][4];
        #pragma unroll
        for (int rb = 0; rb < 2; ++rb)
            #pragma unroll
            for (int cb = 0; cb < 4; ++cb)
                acc[rb][cb] = (f32x4){0.f, 0.f, 0.f, 0.f};

        #pragma unroll
        for (int rb = 0; rb < 2; ++rb) {
            const float* ap = in + (size_t)(r0 + rb * 16 + lrow) * C_;
            float4 ar[8];
            #pragma unroll
            for (int ks = 0; ks < 4; ++ks) {
                ar[2*ks]   = *(const float4*)(ap + ks * 32 + lk8);
                ar[2*ks+1] = *(const float4*)(ap + ks * 32 + lk8 + 4);
            }
            #pragma unroll
            for (int ks = 0; ks < 4; ++ks) {
                const float f[8] = {ar[2*ks].x, ar[2*ks].y, ar[2*ks].z, ar[2*ks].w,
                                    ar[2*ks+1].x, ar[2*ks+1].y, ar[2*ks+1].z, ar[2*ks+1].w};
                bf16x8 ah, al;
                #pragma unroll
                for (int i = 0; i < 8; ++i) {
                    short h, l; split_bf16(f[i], h, l);
                    ah[i] = h; al[i] = l;
                }
                #pragma unroll
                for (int cb = 0; cb < 4; ++cb) {
                    f32x4 t = acc[rb][cb];
                    t = mfma16(Bh[cb][ks], ah, t);   // W first: transposed frag
                    t = mfma16(Bl[cb][ks], ah, t);
                    t = mfma16(Bh[cb][ks], al, t);
                    acc[rb][cb] = t;
                }
            }
        }
        // ---- epilogue: float4 per (rb,cb): row=r0+rb*16+lrow, col=c0+cb*16+oc4 ----
        #pragma unroll
        for (int rb = 0; rb < 2; ++rb) {
            const size_t row = (size_t)r0 + rb * 16 + lrow;
            #pragma unroll
            for (int cb = 0; cb < 4; ++cb) {
                const int col = c0 + cb * 16 + oc4;
                f32x4 v = acc[rb][cb];
                if constexpr (EPI) {
                    const float4 bz = *(const float4*)(bias + col);
                    const float4 rv = *(const float4*)(resid + row * C_ + col);
                    v[0] += bz.x + rv.x; v[1] += bz.y + rv.y;
                    v[2] += bz.z + rv.z; v[3] += bz.w + rv.w;
                    *(f32x4*)(out0 + row * C_ + col) = v;
                } else {
                    float* op = (c0 >= 128) ? out1 : out0;
                    *(f32x4*)(op + row * C_ + (col & 127)) = v;
                }
            }
        }
    }
}

// ============================================================================
// MFMA x_dbl: xd[ST x 32] = u[ST x 128] @ xw_pad[32 x 128]^T  (split-bf16)
// ============================================================================
__global__ __launch_bounds__(256) void k_xdbl(const float* __restrict__ u,
        const unsigned short* __restrict__ xwhi, const unsigned short* __restrict__ xwlo,
        float* __restrict__ xd) {
    const int tid  = threadIdx.x;
    const int wave = tid >> 6, lane = tid & 63;
    const int lrow = lane & 15;
    const int lk8  = (lane >> 4) << 3;
    const int r0   = blockIdx.x * 128 + wave * 32;

    f32x4 acc[2][2];
    #pragma unroll
    for (int rb = 0; rb < 2; ++rb)
        #pragma unroll
        for (int cb = 0; cb < 2; ++cb)
            acc[rb][cb] = (f32x4){0.f, 0.f, 0.f, 0.f};

    const float* a0 = u + (size_t)(r0 + lrow) * C_ + lk8;
    const float* a1 = u + (size_t)(r0 + 16 + lrow) * C_ + lk8;

    #pragma unroll
    for (int ks = 0; ks < 4; ++ks) {
        bf16x8 ah[2], al[2];
        #pragma unroll
        for (int rb = 0; rb < 2; ++rb) {
            const float* ap = (rb ? a1 : a0) + ks * 32;
            const float4 v0 = *(const float4*)ap;
            const float4 v1 = *(const float4*)(ap + 4);
            const float f[8] = {v0.x, v0.y, v0.z, v0.w, v1.x, v1.y, v1.z, v1.w};
            #pragma unroll
            for (int i = 0; i < 8; ++i) {
                short h, l; split_bf16(f[i], h, l);
                ah[rb][i] = h; al[rb][i] = l;
            }
        }
        #pragma unroll
        for (int cb = 0; cb < 2; ++cb) {
            const size_t boff = (size_t)(cb * 16 + lrow) * C_ + ks * 32 + lk8;
            const bf16x8 bh = *(const bf16x8*)(xwhi + boff);
            const bf16x8 bl = *(const bf16x8*)(xwlo + boff);
            #pragma unroll
            for (int rb = 0; rb < 2; ++rb) {
                f32x4 t = acc[rb][cb];
                t = mfma16(ah[rb], bh, t);
                t = mfma16(ah[rb], bl, t);
                t = mfma16(al[rb], bh, t);
                acc[rb][cb] = t;
            }
        }
    }
    #pragma unroll
    for (int rb = 0; rb < 2; ++rb)
        #pragma unroll
        for (int cb = 0; cb < 2; ++cb) {
            const int col = cb * 16 + lrow;
            #pragma unroll
            for (int j = 0; j < 4; ++j) {
                const int row = r0 + rb * 16 + (lane >> 4) * 4 + j;
                xd[(size_t)row * 32 + col] = acc[rb][cb][j];
            }
        }
}

// ============================================================================
// delta/Bs/Cs from xd: fully parallel. Block = 2 rows x 128 c.
// ============================================================================
__global__ __launch_bounds__(256) void k_dbc(const float* __restrict__ xd,
        const float* __restrict__ prompt, const float* __restrict__ dtw,
        const float* __restrict__ dtb, float* __restrict__ delta,
        float* __restrict__ Bsv, float* __restrict__ Csv) {
    const int tid = threadIdx.x;
    const int g = blockIdx.x * 2 + (tid >> 7);     // global active row 0..16383
    const int c = tid & 127;
    const float* xr = xd + (size_t)g * 32;
    float wreg[8];
    *(float4*)&wreg[0] = *(const float4*)(dtw + c*8);
    *(float4*)&wreg[4] = *(const float4*)(dtw + c*8 + 4);
    float dd = dtb[c];
    #pragma unroll
    for (int r = 0; r < 8; ++r) dd += xr[r] * wreg[r];     // broadcast loads
    delta[(size_t)g * C_ + c] = softplus_f(dd);
    if (c < 8) {
        Bsv[(size_t)g * N_ + c] = xr[8 + c];
    } else if (c < 16) {
        const int n = c - 8;
        const int b = g >> 12, s = g & 4095;
        const int l = ((s >> 6) << 7) | (s & 63);
        Csv[(size_t)g * N_ + n] = xr[16 + n] + prompt[((size_t)b*L_ + l)*N_ + n];
    }
}

// ============================================================================
// 2-level Haar DWT, float4-per-thread: block = 8 sites x 32 channel-quads.
// x_proc (B,L,C) -> bands1 [B][3][64][64][C] + compact u. No LDS, no syncs.
// ============================================================================
__global__ __launch_bounds__(256) void k_dwt(const float* __restrict__ xp,
        float* __restrict__ bands, float* __restrict__ u) {
    const int tid = threadIdx.x;
    const int c4 = (tid & 31) << 2;                 // channel quad
    const int sitei = blockIdx.x * 8 + (tid >> 5);  // 0..4095
    const int b = sitei >> 10, p = (sitei >> 5) & 31, q = sitei & 31;
    const float* px = xp + (size_t)b * L_ * C_ + c4;
    f32x4 v[4][4];
    #pragma unroll
    for (int i = 0; i < 4; ++i)
        #pragma unroll
        for (int j = 0; j < 4; ++j)
            v[i][j] = *(const f32x4*)(px + (size_t)(((p<<2)+i)*W_ + (q<<2)+j) * C_);
    const size_t bstride = (size_t)64*64*C_;
    f32x4 ll[2][2];
    #pragma unroll
    for (int di = 0; di < 2; ++di)
        #pragma unroll
        for (int dj = 0; dj < 2; ++dj) {
            const f32x4 a  = v[2*di][2*dj],   bb = v[2*di][2*dj+1];
            const f32x4 cc = v[2*di+1][2*dj], dd = v[2*di+1][2*dj+1];
            ll[di][dj]     = (a+bb+cc+dd)*0.5f;
            const f32x4 lh = (a+bb-cc-dd)*0.5f;
            const f32x4 hl = (a-bb+cc-dd)*0.5f;
            const f32x4 hh = (a-bb-cc+dd)*0.5f;
            const int i1 = (p<<1)+di, j1 = (q<<1)+dj;
            const size_t bb0 = (((size_t)b*3*64 + i1)*64 + j1)*C_ + c4;
            *(f32x4*)(bands + bb0)             = lh;
            *(f32x4*)(bands + bb0 +   bstride) = hl;
            *(f32x4*)(bands + bb0 + 2*bstride) = hh;
        }
    const f32x4 a = ll[0][0], bb = ll[0][1], cc = ll[1][0], dd = ll[1][1];
    const f32x4 l2  = (a+bb+cc+dd)*0.5f;
    const f32x4 lh2 = (a+bb-cc-dd)*0.5f;
    const f32x4 hl2 = (a-bb+cc-dd)*0.5f;
    const f32x4 hh2 = (a-bb-cc+dd)*0.5f;
    const size_t ub = (size_t)b*LS_*C_ + c4;
    *(f32x4*)(u + ub + (size_t)((p<<6)+q)*C_)         = l2;
    *(f32x4*)(u + ub + (size_t)((p<<6)+32+q)*C_)      = lh2;
    *(f32x4*)(u + ub + (size_t)(((32+p)<<6)+q)*C_)    = hl2;
    *(f32x4*)(u + ub + (size_t)(((32+p)<<6)+32+q)*C_) = hh2;
}

// ============================================================================
// Scan pass 1: per (b,c,chunk) summary
// ============================================================================
__global__ __launch_bounds__(256) void k_scan1(const float* __restrict__ delta,
        const float* __restrict__ u, const float* __restrict__ Bsv,
        const float* __restrict__ Alog, float* __restrict__ dsum, float* __restrict__ hend) {
    const int tid = threadIdx.x;
    const int b = blockIdx.x >> 7, k2 = blockIdx.x & 127;
    const int k = (k2 << 1) | (tid >> 7);
    const int c = tid & 127;
    float al[8];
    *(float4*)&al[0] = *(const float4*)(Alog + c*8);
    *(float4*)&al[4] = *(const float4*)(Alog + c*8 + 4);
    float an[8];
    #pragma unroll
    for (int n = 0; n < 8; ++n) an[n] = -__expf(al[n]);
    float h[8] = {0,0,0,0,0,0,0,0};
    float cum = 0.f;
    const int s0 = k << 4;
    for (int t = 0; t < CS_; ++t) {
        const int s = s0 + t;
        const size_t base = ((size_t)b*LS_ + s)*C_ + c;
        const float d  = delta[base];
        const float uu = u[base];
        float bv[8];
        const float4* bp = (const float4*)(Bsv + ((size_t)b*LS_ + s)*N_);
        *(float4*)&bv[0] = bp[0];
        *(float4*)&bv[4] = bp[1];
        cum += d;
        const float du = d * uu;
        #pragma unroll
        for (int n = 0; n < 8; ++n)
            h[n] = __expf(d*an[n])*h[n] + bv[n]*du;
    }
    const size_t idx = (size_t)(b*NC_ + k)*C_ + c;
    dsum[idx] = cum;
    *(float4*)(hend + idx*N_)     = make_float4(h[0],h[1],h[2],h[3]);
    *(float4*)(hend + idx*N_ + 4) = make_float4(h[4],h[5],h[6],h[7]);
}

// ============================================================================
// Scan pass 2: serial combine, double-buffered batch-16 prefetch
// ============================================================================
#define KB_ 16
__global__ __launch_bounds__(256) void k_comb(const float* __restrict__ dsum,
        const float* __restrict__ hend, const float* __restrict__ Alog,
        const float* __restrict__ dtb, float* __restrict__ hin) {
    const int g = blockIdx.x * 256 + threadIdx.x;   // 0..4095
    const int b = g >> 10;
    const int c = (g >> 3) & 127;
    const int n = g & 7;
    const float a  = -__expf(Alog[c*N_ + n]);
    const float d0 = softplus_f(dtb[c]);
    const float dz = __expf(a * (64.f * d0));
    float carry = 0.f;
    float ea[KB_], ha[KB_], eb[KB_], hb[KB_];
    auto LOAD = [&](int kb, float* e, float* hv) {
        #pragma unroll
        for (int j = 0; j < KB_; ++j) {
            const size_t idx = (size_t)(b*NC_ + kb + j)*C_ + c;
            e[j]  = a * dsum[idx];
            hv[j] = hend[idx*N_ + n];
        }
    };
    auto CHAIN = [&](int kb, const float* e, const float* hv) {
        #pragma unroll
        for (int j = 0; j < KB_; ++j) {
            const int k = kb + j;
            if (k && !(k & 3)) carry *= dz;
            hin[((size_t)(b*NC_ + k)*C_ + c)*N_ + n] = carry;
            carry = __expf(e[j])*carry + hv[j];
        }
    };
    LOAD(0, ea, ha);
    for (int kb = 0; kb < NC_; kb += 2*KB_) {
        LOAD(kb + KB_, eb, hb);
        CHAIN(kb, ea, ha);
        if (kb + 2*KB_ < NC_) LOAD(kb + 2*KB_, ea, ha);
        CHAIN(kb + KB_, eb, hb);
    }
}

// ============================================================================
// Scan pass 3: re-run each chunk from true h_in -> h11
// ============================================================================
__global__ __launch_bounds__(256) void k_scan2(const float* __restrict__ delta,
        const float* __restrict__ u, const float* __restrict__ Bsv,
        const float* __restrict__ Csv, const float* __restrict__ Alog,
        const float* __restrict__ Ds, const float* __restrict__ hin,
        float* __restrict__ h11) {
    const int tid = threadIdx.x;
    const int b = blockIdx.x >> 7, k2 = blockIdx.x & 127;
    const int k = (k2 << 1) | (tid >> 7);
    const int c = tid & 127;
    float al[8];
    *(float4*)&al[0] = *(const float4*)(Alog + c*8);
    *(float4*)&al[4] = *(const float4*)(Alog + c*8 + 4);
    float an[8];
    #pragma unroll
    for (int n = 0; n < 8; ++n) an[n] = -__expf(al[n]);
    float h[8];
    const float4* hp = (const float4*)(hin + ((size_t)(b*NC_ + k)*C_ + c)*N_);
    *(float4*)&h[0] = hp[0];
    *(float4*)&h[4] = hp[1];
    const float dsc = Ds[c];
    const int s0 = k << 4;
    for (int t = 0; t < CS_; ++t) {
        const int s = s0 + t;
        const size_t base = ((size_t)b*LS_ + s)*C_ + c;
        const float d  = delta[base];
        const float uu = u[base];
        float bv[8], cv[8];
        const float4* bp = (const float4*)(Bsv + ((size_t)b*LS_ + s)*N_);
        const float4* cp = (const float4*)(Csv + ((size_t)b*LS_ + s)*N_);
        *(float4*)&bv[0] = bp[0];
        *(float4*)&bv[4] = bp[1];
        *(float4*)&cv[0] = cp[0];
        *(float4*)&cv[4] = cp[1];
        const float du = d * uu;
        float y = uu * dsc;
        #pragma unroll
        for (int n = 0; n < 8; ++n) {
            h[n] = __expf(d*an[n])*h[n] + bv[n]*du;
            y += h[n] * cv[n];
        }
        h11[base] = y;
    }
}

// ============================================================================
// Fused 2-level inverse Haar DWT + LayerNorm + SiLU gate, float4-per-thread.
// Block = 8 sites x 32 channel-quads; stats via 32-lane shfl reduce. No LDS.
// ============================================================================
__global__ __launch_bounds__(256) void k_idwt_ln(const float* __restrict__ h11,
        const float* __restrict__ bands, const float* __restrict__ z,
        const float* __restrict__ gamma, const float* __restrict__ beta,
        float* __restrict__ yout) {
    const int tid = threadIdx.x;
    const int c4 = (tid & 31) << 2;
    const int sitei = blockIdx.x * 8 + (tid >> 5);
    const int b = sitei >> 10, p = (sitei >> 5) & 31, q = sitei & 31;
    const size_t ub = (size_t)b*LS_*C_ + c4;
    const f32x4 l2  = *(const f32x4*)(h11 + ub + (size_t)((p<<6)+q)*C_);
    const f32x4 lh2 = *(const f32x4*)(h11 + ub + (size_t)((p<<6)+32+q)*C_);
    const f32x4 hl2 = *(const f32x4*)(h11 + ub + (size_t)(((32+p)<<6)+q)*C_);
    const f32x4 hh2 = *(const f32x4*)(h11 + ub + (size_t)(((32+p)<<6)+32+q)*C_);
    f32x4 yl1[2][2];
    yl1[0][0] = (l2+lh2+hl2+hh2)*0.5f;
    yl1[0][1] = (l2+lh2-hl2-hh2)*0.5f;
    yl1[1][0] = (l2-lh2+hl2-hh2)*0.5f;
    yl1[1][1] = (l2-lh2-hl2+hh2)*0.5f;
    const size_t bstride = (size_t)64*64*C_;
    f32x4 v[16];
    #pragma unroll
    for (int di = 0; di < 2; ++di)
        #pragma unroll
        for (int dj = 0; dj < 2; ++dj) {
            const int i1 = (p<<1)+di, j1 = (q<<1)+dj;
            const size_t bb0 = (((size_t)b*3*64 + i1)*64 + j1)*C_ + c4;
            const f32x4 lh = *(const f32x4*)(bands + bb0);
            const f32x4 hl = *(const f32x4*)(bands + bb0 +   bstride);
            const f32x4 hh = *(const f32x4*)(bands + bb0 + 2*bstride);
            const f32x4 ll = yl1[di][dj];
            v[(2*di+0)*4 + 2*dj+0] = (ll+lh+hl+hh)*0.5f;
            v[(2*di+0)*4 + 2*dj+1] = (ll+lh-hl-hh)*0.5f;
            v[(2*di+1)*4 + 2*dj+0] = (ll-lh+hl-hh)*0.5f;
            v[(2*di+1)*4 + 2*dj+1] = (ll-lh-hl+hh)*0.5f;
        }
    // per-pixel stats over C=128: lane-local 4-channel partial, then 32-lane reduce
    float sm[16], sq[16];
    #pragma unroll
    for (int p16 = 0; p16 < 16; ++p16) {
        const f32x4 t = v[p16];
        float s  = t[0]+t[1]+t[2]+t[3];
        float ss = t[0]*t[0]+t[1]*t[1]+t[2]*t[2]+t[3]*t[3];
        #pragma unroll
        for (int off = 1; off < 32; off <<= 1) {
            s  += __shfl_xor(s,  off);
            ss += __shfl_xor(ss, off);
        }
        sm[p16] = s; sq[p16] = ss;
    }
    const f32x4 gm = *(const f32x4*)(gamma + c4);
    const f32x4 bt = *(const f32x4*)(beta  + c4);
    #pragma unroll
    for (int p16 = 0; p16 < 16; ++p16) {
        const int lr = p16 >> 2, lc = p16 & 3;
        const size_t l = (size_t)((p<<2)+lr)*W_ + (q<<2)+lc;
        const float mu  = sm[p16] * 0.0078125f;
        const float var = sq[p16] * 0.0078125f - mu*mu;
        const float ri  = rsqrtf(var + 1e-5f);
        const f32x4 zv = *(const f32x4*)(z + ((size_t)b*L_ + l)*C_ + c4);
        f32x4 y = (v[p16] - mu) * ri * gm + bt;
        #pragma unroll
        for (int e = 0; e < 4; ++e)
            y[e] *= zv[e] / (1.f + __expf(-zv[e]));
        *(f32x4*)(yout + ((size_t)b*L_ + l)*C_ + c4) = y;
    }
}

// ============================================================================
extern "C" void kernel_launch(void* const* d_in, const int* in_sizes, int n_in,
                              void* d_out, int out_size, void* d_ws, size_t ws_size,
                              hipStream_t stream) {
    (void)in_sizes; (void)n_in; (void)out_size; (void)ws_size;
    const float* x      = (const float*)d_in[0];
    const float* prompt = (const float*)d_in[1];
    const float* in_w   = (const float*)d_in[2];
    const float* x_w    = (const float*)d_in[3];
    const float* dt_w   = (const float*)d_in[4];
    const float* dt_b   = (const float*)d_in[5];
    const float* A_logs = (const float*)d_in[6];
    const float* Ds     = (const float*)d_in[7];
    const float* gam    = (const float*)d_in[8];
    const float* bet    = (const float*)d_in[9];
    const float* out_w  = (const float*)d_in[10];
    const float* out_b  = (const float*)d_in[11];
    float* wsp   = (float*)d_ws;
    float* xproc = wsp + OFF_XPROC;   // later reused for gated y
    float* z     = wsp + OFF_Z;
    float* bands = wsp + OFF_BANDS;
    float* u     = wsp + OFF_U;
    float* delta = wsp + OFF_DELTA;
    float* Bs    = wsp + OFF_BS;
    float* Cs    = wsp + OFF_CS;
    float* dsum  = wsp + OFF_DSUM;
    float* hend  = wsp + OFF_HEND;
    float* hin   = wsp + OFF_HIN;
    float* h11   = wsp + OFF_H11;
    float* xd    = wsp + OFF_XDBL;
    unsigned short* wq = (unsigned short*)(wsp + OFF_WCVT);
    unsigned short* whi_in  = wq;
    unsigned short* wlo_in  = wq + 32768;
    unsigned short* whi_out = wq + 65536;
    unsigned short* wlo_out = wq + 81920;
    unsigned short* whi_xw  = wq + 98304;
    unsigned short* wlo_xw  = wq + 102400;
    float* out   = (float*)d_out;

    // 0) split weights into bf16 hi/lo
    k_cvt<<<208, 256, 0, stream>>>(in_w, out_w, x_w, wq);
    // 1) in_proj GEMM (MFMA, weights-in-regs, 3 blocks/CU) -> x_proc, z
    k_gemm2<false><<<768, 256, 0, stream>>>(x, whi_in, wlo_in, xproc, z, nullptr, nullptr);
    // 2) 2-level DWT -> bands1 + compact active-region u
    k_dwt<<<512, 256, 0, stream>>>(xproc, bands, u);
    // 3a) x_dbl = u @ x_proj^T (MFMA)
    k_xdbl<<<128, 256, 0, stream>>>(u, whi_xw, wlo_xw, xd);
    // 3b) delta / Bs / Cs (fully parallel)
    k_dbc<<<8192, 256, 0, stream>>>(xd, prompt, dt_w, dt_b, delta, Bs, Cs);
    // 4) chunked scan: summaries
    k_scan1<<<512, 256, 0, stream>>>(delta, u, Bs, A_logs, dsum, hend);
    // 5) serial combine across chunk boundaries
    k_comb<<<16, 256, 0, stream>>>(dsum, hend, A_logs, dt_b, hin);
    // 6) re-scan with true initial states -> h11
    k_scan2<<<512, 256, 0, stream>>>(delta, u, Bs, Cs, A_logs, Ds, hin, h11);
    // 7) fused inverse DWT + LayerNorm + SiLU gate -> y (xproc buffer)
    k_idwt_ln<<<512, 256, 0, stream>>>(h11, bands, z, gam, bet, xproc);
    // 8) out_proj GEMM + bias + residual -> d_out
    k_gemm2<true><<<768, 256, 0, stream>>>(xproc, whi_out, wlo_out, out, nullptr, out_b, x);
}

// Round 7
// 232.377 us; speedup vs baseline: 1.5407x; 1.5407x over previous
//
#include <hip/hip_runtime.h>

// Problem constants (fixed by setup_inputs)
#define B_   4
#define H_   128
#define W_   128
#define L_   (H_*W_)        // 16384
#define C_   128
#define N_   8
#define R_   8
#define LS_  4096           // active scan positions per batch (64x64 top-left region)
#define CS_  16             // scan chunk length (steps)
#define NC_  256            // chunks per (b,c) = LS_/CS_
#define ST_  (B_*LS_)       // 16384 total active rows

// ---- workspace layout (in floats) ----
#define OFF_XPROC 0ull
#define OFF_Z     (OFF_XPROC + (size_t)B_*L_*C_)
#define OFF_BANDS (OFF_Z     + (size_t)B_*L_*C_)                 // bands1: [B][3][64][64][C]
#define OFF_U     (OFF_BANDS + (size_t)B_*3*64*64*C_)            // u  [B][4096][C]
#define OFF_DELTA (OFF_U     + (size_t)B_*LS_*C_)
#define OFF_BS    (OFF_DELTA + (size_t)B_*LS_*C_)                // [B][4096][8]
#define OFF_CS    (OFF_BS    + (size_t)B_*LS_*N_)
#define OFF_DSUM  (OFF_CS    + (size_t)B_*LS_*N_)                // [B][NC][C]
#define OFF_HEND  (OFF_DSUM  + (size_t)B_*NC_*C_)                // [B][NC][C][8]
#define OFF_HIN   (OFF_HEND  + (size_t)B_*NC_*C_*N_)
#define OFF_H11   (OFF_HIN   + (size_t)B_*NC_*C_*N_)             // [B][4096][C]
#define OFF_XDBL  (OFF_H11   + (size_t)B_*LS_*C_)                // [ST][32] fp32
#define OFF_WCVT  (OFF_XDBL  + (size_t)ST_*32)                   // ushort region: split weights

typedef __attribute__((ext_vector_type(8))) short bf16x8;
typedef __attribute__((ext_vector_type(4))) float f32x4;

__device__ __forceinline__ float softplus_f(float x) {
    return (x > 20.f) ? x : log1pf(__expf(x));
}

// split fp32 into bf16 hi (round-nearest) + bf16 lo (truncated residual)
__device__ __forceinline__ void split_bf16(float x, short& h, short& l) {
    const unsigned u  = __float_as_uint(x);
    const unsigned hr = (u + 0x7FFFu + ((u >> 16) & 1u)) >> 16;
    h = (short)hr;
    const float hf = __uint_as_float(hr << 16);
    l = (short)(__float_as_uint(x - hf) >> 16);
}

__device__ __forceinline__ f32x4 mfma16(bf16x8 a, bf16x8 b, f32x4 c) {
    return __builtin_amdgcn_mfma_f32_16x16x32_bf16(a, b, c, 0, 0, 0);
}

// ============================================================================
// Weight split: in_proj (256x128), out_proj (128x128), x_proj (24x128 pad 32)
// ============================================================================
__global__ __launch_bounds__(256) void k_cvt(const float* __restrict__ w_in,
        const float* __restrict__ w_out, const float* __restrict__ xw,
        unsigned short* __restrict__ wq) {
    const int i = blockIdx.x * 256 + threadIdx.x;   // 0..53247
    float v; unsigned short *hi, *lo; int idx;
    if (i < 32768)      { v = w_in[i];          hi = wq;         lo = wq + 32768;  idx = i; }
    else if (i < 49152) { v = w_out[i - 32768]; hi = wq + 65536; lo = wq + 81920;  idx = i - 32768; }
    else {
        idx = i - 49152;                         // 0..4095 over [32][128]
        v = (idx < 24*128) ? xw[idx] : 0.f;      // zero-pad rows 24..31
        hi = wq + 98304; lo = wq + 102400;
    }
    short h, l; split_bf16(v, h, l);
    hi[idx] = (unsigned short)h;
    lo[idx] = (unsigned short)l;
}

// ============================================================================
// MFMA split-bf16 GEMM, weights-in-registers, persistent grid-stride.
// EXACT round-4 configuration: __launch_bounds__(256,2), grid 512.
// NOTE: bounds(256,3) spills the B panel (r6: VGPR 128->84, HBM 84->305MB).
// out[M x NJ] = in[M x 128] @ w[NJ x 128]^T
//   !EPI: NJ=256, 4 waves side-by-side (wave tile 32x64), chunk = 32 rows.
//   EPI : NJ=128, 2x2 waves, chunk = 64 rows, + bias + resid -> out0.
// Swapped-operand MFMA (W first) => lane's 4 acc regs = 4 consecutive out
// cols of ONE row => float4 stores.
// ============================================================================
template<bool EPI>
__global__ __launch_bounds__(256, 2) void k_gemm2(const float* __restrict__ in,
        const unsigned short* __restrict__ whi, const unsigned short* __restrict__ wlo,
        float* __restrict__ out0, float* __restrict__ out1,
        const float* __restrict__ bias, const float* __restrict__ resid) {
    const int tid  = threadIdx.x;
    const int wave = tid >> 6, lane = tid & 63;
    const int lrow = lane & 15;           // weight-row / A-row lane index
    const int lk8  = (lane >> 4) << 3;    // k-offset within 32-k step
    const int oc4  = (lane >> 4) << 2;    // output-col sub-offset for stores

    int c0, wr;
    if constexpr (EPI) { c0 = (wave & 1) * 64; wr = wave >> 1; }
    else               { c0 = wave * 64;       wr = 0; }

    // ---- preload this wave's B panel (64 cols x K=128, hi+lo) into regs ----
    bf16x8 Bh[4][4], Bl[4][4];
    #pragma unroll
    for (int cb = 0; cb < 4; ++cb)
        #pragma unroll
        for (int ks = 0; ks < 4; ++ks) {
            const size_t boff = (size_t)(c0 + cb * 16 + lrow) * C_ + ks * 32 + lk8;
            Bh[cb][ks] = *(const bf16x8*)(whi + boff);
            Bl[cb][ks] = *(const bf16x8*)(wlo + boff);
        }

    const int nch = EPI ? 1024 : 2048;    // chunks of (EPI?64:32) rows; M=65536
    for (int ch = blockIdx.x; ch < nch; ch += gridDim.x) {
        const int r0 = EPI ? (ch * 64 + wr * 32) : ch * 32;
        f32x4 acc[2][4];
        #pragma unroll
        for (int rb = 0; rb < 2; ++rb)
            #pragma unroll
            for (int cb = 0; cb < 4; ++cb)
                acc[rb][cb] = (f32x4){0.f, 0.f, 0.f, 0.f};

        #pragma unroll
        for (int rb = 0; rb < 2; ++rb) {
            const float* ap = in + (size_t)(r0 + rb * 16 + lrow) * C_;
            float4 ar[8];
            #pragma unroll
            for (int ks = 0; ks < 4; ++ks) {
                ar[2*ks]   = *(const float4*)(ap + ks * 32 + lk8);
                ar[2*ks+1] = *(const float4*)(ap + ks * 32 + lk8 + 4);
            }
            #pragma unroll
            for (int ks = 0; ks < 4; ++ks) {
                const float f[8] = {ar[2*ks].x, ar[2*ks].y, ar[2*ks].z, ar[2*ks].w,
                                    ar[2*ks+1].x, ar[2*ks+1].y, ar[2*ks+1].z, ar[2*ks+1].w};
                bf16x8 ah, al;
                #pragma unroll
                for (int i = 0; i < 8; ++i) {
                    short h, l; split_bf16(f[i], h, l);
                    ah[i] = h; al[i] = l;
                }
                #pragma unroll
                for (int cb = 0; cb < 4; ++cb) {
                    f32x4 t = acc[rb][cb];
                    t = mfma16(Bh[cb][ks], ah, t);   // W first: transposed frag
                    t = mfma16(Bl[cb][ks], ah, t);
                    t = mfma16(Bh[cb][ks], al, t);
                    acc[rb][cb] = t;
                }
            }
        }
        // ---- epilogue: float4 per (rb,cb): row=r0+rb*16+lrow, col=c0+cb*16+oc4 ----
        #pragma unroll
        for (int rb = 0; rb < 2; ++rb) {
            const size_t row = (size_t)r0 + rb * 16 + lrow;
            #pragma unroll
            for (int cb = 0; cb < 4; ++cb) {
                const int col = c0 + cb * 16 + oc4;
                f32x4 v = acc[rb][cb];
                if constexpr (EPI) {
                    const float4 bz = *(const float4*)(bias + col);
                    const float4 rv = *(const float4*)(resid + row * C_ + col);
                    v[0] += bz.x + rv.x; v[1] += bz.y + rv.y;
                    v[2] += bz.z + rv.z; v[3] += bz.w + rv.w;
                    *(f32x4*)(out0 + row * C_ + col) = v;
                } else {
                    float* op = (c0 >= 128) ? out1 : out0;
                    *(f32x4*)(op + row * C_ + (col & 127)) = v;
                }
            }
        }
    }
}

// ============================================================================
// MFMA x_dbl: xd[ST x 32] = u[ST x 128] @ xw_pad[32 x 128]^T  (split-bf16)
// ============================================================================
__global__ __launch_bounds__(256) void k_xdbl(const float* __restrict__ u,
        const unsigned short* __restrict__ xwhi, const unsigned short* __restrict__ xwlo,
        float* __restrict__ xd) {
    const int tid  = threadIdx.x;
    const int wave = tid >> 6, lane = tid & 63;
    const int lrow = lane & 15;
    const int lk8  = (lane >> 4) << 3;
    const int r0   = blockIdx.x * 128 + wave * 32;

    f32x4 acc[2][2];
    #pragma unroll
    for (int rb = 0; rb < 2; ++rb)
        #pragma unroll
        for (int cb = 0; cb < 2; ++cb)
            acc[rb][cb] = (f32x4){0.f, 0.f, 0.f, 0.f};

    const float* a0 = u + (size_t)(r0 + lrow) * C_ + lk8;
    const float* a1 = u + (size_t)(r0 + 16 + lrow) * C_ + lk8;

    #pragma unroll
    for (int ks = 0; ks < 4; ++ks) {
        bf16x8 ah[2], al[2];
        #pragma unroll
        for (int rb = 0; rb < 2; ++rb) {
            const float* ap = (rb ? a1 : a0) + ks * 32;
            const float4 v0 = *(const float4*)ap;
            const float4 v1 = *(const float4*)(ap + 4);
            const float f[8] = {v0.x, v0.y, v0.z, v0.w, v1.x, v1.y, v1.z, v1.w};
            #pragma unroll
            for (int i = 0; i < 8; ++i) {
                short h, l; split_bf16(f[i], h, l);
                ah[rb][i] = h; al[rb][i] = l;
            }
        }
        #pragma unroll
        for (int cb = 0; cb < 2; ++cb) {
            const size_t boff = (size_t)(cb * 16 + lrow) * C_ + ks * 32 + lk8;
            const bf16x8 bh = *(const bf16x8*)(xwhi + boff);
            const bf16x8 bl = *(const bf16x8*)(xwlo + boff);
            #pragma unroll
            for (int rb = 0; rb < 2; ++rb) {
                f32x4 t = acc[rb][cb];
                t = mfma16(ah[rb], bh, t);
                t = mfma16(ah[rb], bl, t);
                t = mfma16(al[rb], bh, t);
                acc[rb][cb] = t;
            }
        }
    }
    #pragma unroll
    for (int rb = 0; rb < 2; ++rb)
        #pragma unroll
        for (int cb = 0; cb < 2; ++cb) {
            const int col = cb * 16 + lrow;
            #pragma unroll
            for (int j = 0; j < 4; ++j) {
                const int row = r0 + rb * 16 + (lane >> 4) * 4 + j;
                xd[(size_t)row * 32 + col] = acc[rb][cb][j];
            }
        }
}

// ============================================================================
// delta/Bs/Cs from xd: fully parallel. Block = 2 rows x 128 c.
// ============================================================================
__global__ __launch_bounds__(256) void k_dbc(const float* __restrict__ xd,
        const float* __restrict__ prompt, const float* __restrict__ dtw,
        const float* __restrict__ dtb, float* __restrict__ delta,
        float* __restrict__ Bsv, float* __restrict__ Csv) {
    const int tid = threadIdx.x;
    const int g = blockIdx.x * 2 + (tid >> 7);     // global active row 0..16383
    const int c = tid & 127;
    const float* xr = xd + (size_t)g * 32;
    float wreg[8];
    *(float4*)&wreg[0] = *(const float4*)(dtw + c*8);
    *(float4*)&wreg[4] = *(const float4*)(dtw + c*8 + 4);
    float dd = dtb[c];
    #pragma unroll
    for (int r = 0; r < 8; ++r) dd += xr[r] * wreg[r];     // broadcast loads
    delta[(size_t)g * C_ + c] = softplus_f(dd);
    if (c < 8) {
        Bsv[(size_t)g * N_ + c] = xr[8 + c];
    } else if (c < 16) {
        const int n = c - 8;
        const int b = g >> 12, s = g & 4095;
        const int l = ((s >> 6) << 7) | (s & 63);
        Csv[(size_t)g * N_ + n] = xr[16 + n] + prompt[((size_t)b*L_ + l)*N_ + n];
    }
}

// ============================================================================
// 2-level Haar DWT, float4-per-thread: block = 8 sites x 32 channel-quads.
// x_proc (B,L,C) -> bands1 [B][3][64][64][C] + compact u. No LDS, no syncs.
// ============================================================================
__global__ __launch_bounds__(256) void k_dwt(const float* __restrict__ xp,
        float* __restrict__ bands, float* __restrict__ u) {
    const int tid = threadIdx.x;
    const int c4 = (tid & 31) << 2;                 // channel quad
    const int sitei = blockIdx.x * 8 + (tid >> 5);  // 0..4095
    const int b = sitei >> 10, p = (sitei >> 5) & 31, q = sitei & 31;
    const float* px = xp + (size_t)b * L_ * C_ + c4;
    f32x4 v[4][4];
    #pragma unroll
    for (int i = 0; i < 4; ++i)
        #pragma unroll
        for (int j = 0; j < 4; ++j)
            v[i][j] = *(const f32x4*)(px + (size_t)(((p<<2)+i)*W_ + (q<<2)+j) * C_);
    const size_t bstride = (size_t)64*64*C_;
    f32x4 ll[2][2];
    #pragma unroll
    for (int di = 0; di < 2; ++di)
        #pragma unroll
        for (int dj = 0; dj < 2; ++dj) {
            const f32x4 a  = v[2*di][2*dj],   bb = v[2*di][2*dj+1];
            const f32x4 cc = v[2*di+1][2*dj], dd = v[2*di+1][2*dj+1];
            ll[di][dj]     = (a+bb+cc+dd)*0.5f;
            const f32x4 lh = (a+bb-cc-dd)*0.5f;
            const f32x4 hl = (a-bb+cc-dd)*0.5f;
            const f32x4 hh = (a-bb-cc+dd)*0.5f;
            const int i1 = (p<<1)+di, j1 = (q<<1)+dj;
            const size_t bb0 = (((size_t)b*3*64 + i1)*64 + j1)*C_ + c4;
            *(f32x4*)(bands + bb0)             = lh;
            *(f32x4*)(bands + bb0 +   bstride) = hl;
            *(f32x4*)(bands + bb0 + 2*bstride) = hh;
        }
    const f32x4 a = ll[0][0], bb = ll[0][1], cc = ll[1][0], dd = ll[1][1];
    const f32x4 l2  = (a+bb+cc+dd)*0.5f;
    const f32x4 lh2 = (a+bb-cc-dd)*0.5f;
    const f32x4 hl2 = (a-bb+cc-dd)*0.5f;
    const f32x4 hh2 = (a-bb-cc+dd)*0.5f;
    const size_t ub = (size_t)b*LS_*C_ + c4;
    *(f32x4*)(u + ub + (size_t)((p<<6)+q)*C_)         = l2;
    *(f32x4*)(u + ub + (size_t)((p<<6)+32+q)*C_)      = lh2;
    *(f32x4*)(u + ub + (size_t)(((32+p)<<6)+q)*C_)    = hl2;
    *(f32x4*)(u + ub + (size_t)(((32+p)<<6)+32+q)*C_) = hh2;
}

// ============================================================================
// Scan pass 1: per (b,c,chunk) summary
// ============================================================================
__global__ __launch_bounds__(256) void k_scan1(const float* __restrict__ delta,
        const float* __restrict__ u, const float* __restrict__ Bsv,
        const float* __restrict__ Alog, float* __restrict__ dsum, float* __restrict__ hend) {
    const int tid = threadIdx.x;
    const int b = blockIdx.x >> 7, k2 = blockIdx.x & 127;
    const int k = (k2 << 1) | (tid >> 7);
    const int c = tid & 127;
    float al[8];
    *(float4*)&al[0] = *(const float4*)(Alog + c*8);
    *(float4*)&al[4] = *(const float4*)(Alog + c*8 + 4);
    float an[8];
    #pragma unroll
    for (int n = 0; n < 8; ++n) an[n] = -__expf(al[n]);
    float h[8] = {0,0,0,0,0,0,0,0};
    float cum = 0.f;
    const int s0 = k << 4;
    for (int t = 0; t < CS_; ++t) {
        const int s = s0 + t;
        const size_t base = ((size_t)b*LS_ + s)*C_ + c;
        const float d  = delta[base];
        const float uu = u[base];
        float bv[8];
        const float4* bp = (const float4*)(Bsv + ((size_t)b*LS_ + s)*N_);
        *(float4*)&bv[0] = bp[0];
        *(float4*)&bv[4] = bp[1];
        cum += d;
        const float du = d * uu;
        #pragma unroll
        for (int n = 0; n < 8; ++n)
            h[n] = __expf(d*an[n])*h[n] + bv[n]*du;
    }
    const size_t idx = (size_t)(b*NC_ + k)*C_ + c;
    dsum[idx] = cum;
    *(float4*)(hend + idx*N_)     = make_float4(h[0],h[1],h[2],h[3]);
    *(float4*)(hend + idx*N_ + 4) = make_float4(h[4],h[5],h[6],h[7]);
}

// ============================================================================
// Scan pass 2: serial combine, double-buffered batch-16 prefetch
// ============================================================================
#define KB_ 16
__global__ __launch_bounds__(256) void k_comb(const float* __restrict__ dsum,
        const float* __restrict__ hend, const float* __restrict__ Alog,
        const float* __restrict__ dtb, float* __restrict__ hin) {
    const int g = blockIdx.x * 256 + threadIdx.x;   // 0..4095
    const int b = g >> 10;
    const int c = (g >> 3) & 127;
    const int n = g & 7;
    const float a  = -__expf(Alog[c*N_ + n]);
    const float d0 = softplus_f(dtb[c]);
    const float dz = __expf(a * (64.f * d0));
    float carry = 0.f;
    float ea[KB_], ha[KB_], eb[KB_], hb[KB_];
    auto LOAD = [&](int kb, float* e, float* hv) {
        #pragma unroll
        for (int j = 0; j < KB_; ++j) {
            const size_t idx = (size_t)(b*NC_ + kb + j)*C_ + c;
            e[j]  = a * dsum[idx];
            hv[j] = hend[idx*N_ + n];
        }
    };
    auto CHAIN = [&](int kb, const float* e, const float* hv) {
        #pragma unroll
        for (int j = 0; j < KB_; ++j) {
            const int k = kb + j;
            if (k && !(k & 3)) carry *= dz;
            hin[((size_t)(b*NC_ + k)*C_ + c)*N_ + n] = carry;
            carry = __expf(e[j])*carry + hv[j];
        }
    };
    LOAD(0, ea, ha);
    for (int kb = 0; kb < NC_; kb += 2*KB_) {
        LOAD(kb + KB_, eb, hb);
        CHAIN(kb, ea, ha);
        if (kb + 2*KB_ < NC_) LOAD(kb + 2*KB_, ea, ha);
        CHAIN(kb + KB_, eb, hb);
    }
}

// ============================================================================
// Scan pass 3: re-run each chunk from true h_in -> h11
// ============================================================================
__global__ __launch_bounds__(256) void k_scan2(const float* __restrict__ delta,
        const float* __restrict__ u, const float* __restrict__ Bsv,
        const float* __restrict__ Csv, const float* __restrict__ Alog,
        const float* __restrict__ Ds, const float* __restrict__ hin,
        float* __restrict__ h11) {
    const int tid = threadIdx.x;
    const int b = blockIdx.x >> 7, k2 = blockIdx.x & 127;
    const int k = (k2 << 1) | (tid >> 7);
    const int c = tid & 127;
    float al[8];
    *(float4*)&al[0] = *(const float4*)(Alog + c*8);
    *(float4*)&al[4] = *(const float4*)(Alog + c*8 + 4);
    float an[8];
    #pragma unroll
    for (int n = 0; n < 8; ++n) an[n] = -__expf(al[n]);
    float h[8];
    const float4* hp = (const float4*)(hin + ((size_t)(b*NC_ + k)*C_ + c)*N_);
    *(float4*)&h[0] = hp[0];
    *(float4*)&h[4] = hp[1];
    const float dsc = Ds[c];
    const int s0 = k << 4;
    for (int t = 0; t < CS_; ++t) {
        const int s = s0 + t;
        const size_t base = ((size_t)b*LS_ + s)*C_ + c;
        const float d  = delta[base];
        const float uu = u[base];
        float bv[8], cv[8];
        const float4* bp = (const float4*)(Bsv + ((size_t)b*LS_ + s)*N_);
        const float4* cp = (const float4*)(Csv + ((size_t)b*LS_ + s)*N_);
        *(float4*)&bv[0] = bp[0];
        *(float4*)&bv[4] = bp[1];
        *(float4*)&cv[0] = cp[0];
        *(float4*)&cv[4] = cp[1];
        const float du = d * uu;
        float y = uu * dsc;
        #pragma unroll
        for (int n = 0; n < 8; ++n) {
            h[n] = __expf(d*an[n])*h[n] + bv[n]*du;
            y += h[n] * cv[n];
        }
        h11[base] = y;
    }
}

// ============================================================================
// Fused 2-level inverse Haar DWT + LayerNorm + SiLU gate, float4-per-thread.
// Block = 8 sites x 32 channel-quads; stats via 32-lane shfl reduce. No LDS.
// ============================================================================
__global__ __launch_bounds__(256) void k_idwt_ln(const float* __restrict__ h11,
        const float* __restrict__ bands, const float* __restrict__ z,
        const float* __restrict__ gamma, const float* __restrict__ beta,
        float* __restrict__ yout) {
    const int tid = threadIdx.x;
    const int c4 = (tid & 31) << 2;
    const int sitei = blockIdx.x * 8 + (tid >> 5);
    const int b = sitei >> 10, p = (sitei >> 5) & 31, q = sitei & 31;
    const size_t ub = (size_t)b*LS_*C_ + c4;
    const f32x4 l2  = *(const f32x4*)(h11 + ub + (size_t)((p<<6)+q)*C_);
    const f32x4 lh2 = *(const f32x4*)(h11 + ub + (size_t)((p<<6)+32+q)*C_);
    const f32x4 hl2 = *(const f32x4*)(h11 + ub + (size_t)(((32+p)<<6)+q)*C_);
    const f32x4 hh2 = *(const f32x4*)(h11 + ub + (size_t)(((32+p)<<6)+32+q)*C_);
    f32x4 yl1[2][2];
    yl1[0][0] = (l2+lh2+hl2+hh2)*0.5f;
    yl1[0][1] = (l2+lh2-hl2-hh2)*0.5f;
    yl1[1][0] = (l2-lh2+hl2-hh2)*0.5f;
    yl1[1][1] = (l2-lh2-hl2+hh2)*0.5f;
    const size_t bstride = (size_t)64*64*C_;
    f32x4 v[16];
    #pragma unroll
    for (int di = 0; di < 2; ++di)
        #pragma unroll
        for (int dj = 0; dj < 2; ++dj) {
            const int i1 = (p<<1)+di, j1 = (q<<1)+dj;
            const size_t bb0 = (((size_t)b*3*64 + i1)*64 + j1)*C_ + c4;
            const f32x4 lh = *(const f32x4*)(bands + bb0);
            const f32x4 hl = *(const f32x4*)(bands + bb0 +   bstride);
            const f32x4 hh = *(const f32x4*)(bands + bb0 + 2*bstride);
            const f32x4 ll = yl1[di][dj];
            v[(2*di+0)*4 + 2*dj+0] = (ll+lh+hl+hh)*0.5f;
            v[(2*di+0)*4 + 2*dj+1] = (ll+lh-hl-hh)*0.5f;
            v[(2*di+1)*4 + 2*dj+0] = (ll-lh+hl-hh)*0.5f;
            v[(2*di+1)*4 + 2*dj+1] = (ll-lh-hl+hh)*0.5f;
        }
    // per-pixel stats over C=128: lane-local 4-channel partial, then 32-lane reduce
    float sm[16], sq[16];
    #pragma unroll
    for (int p16 = 0; p16 < 16; ++p16) {
        const f32x4 t = v[p16];
        float s  = t[0]+t[1]+t[2]+t[3];
        float ss = t[0]*t[0]+t[1]*t[1]+t[2]*t[2]+t[3]*t[3];
        #pragma unroll
        for (int off = 1; off < 32; off <<= 1) {
            s  += __shfl_xor(s,  off);
            ss += __shfl_xor(ss, off);
        }
        sm[p16] = s; sq[p16] = ss;
    }
    const f32x4 gm = *(const f32x4*)(gamma + c4);
    const f32x4 bt = *(const f32x4*)(beta  + c4);
    #pragma unroll
    for (int p16 = 0; p16 < 16; ++p16) {
        const int lr = p16 >> 2, lc = p16 & 3;
        const size_t l = (size_t)((p<<2)+lr)*W_ + (q<<2)+lc;
        const float mu  = sm[p16] * 0.0078125f;
        const float var = sq[p16] * 0.0078125f - mu*mu;
        const float ri  = rsqrtf(var + 1e-5f);
        const f32x4 zv = *(const f32x4*)(z + ((size_t)b*L_ + l)*C_ + c4);
        f32x4 y = (v[p16] - mu) * ri * gm + bt;
        #pragma unroll
        for (int e = 0; e < 4; ++e)
            y[e] *= zv[e] / (1.f + __expf(-zv[e]));
        *(f32x4*)(yout + ((size_t)b*L_ + l)*C_ + c4) = y;
    }
}

// ============================================================================
extern "C" void kernel_launch(void* const* d_in, const int* in_sizes, int n_in,
                              void* d_out, int out_size, void* d_ws, size_t ws_size,
                              hipStream_t stream) {
    (void)in_sizes; (void)n_in; (void)out_size; (void)ws_size;
    const float* x      = (const float*)d_in[0];
    const float* prompt = (const float*)d_in[1];
    const float* in_w   = (const float*)d_in[2];
    const float* x_w    = (const float*)d_in[3];
    const float* dt_w   = (const float*)d_in[4];
    const float* dt_b   = (const float*)d_in[5];
    const float* A_logs = (const float*)d_in[6];
    const float* Ds     = (const float*)d_in[7];
    const float* gam    = (const float*)d_in[8];
    const float* bet    = (const float*)d_in[9];
    const float* out_w  = (const float*)d_in[10];
    const float* out_b  = (const float*)d_in[11];
    float* wsp   = (float*)d_ws;
    float* xproc = wsp + OFF_XPROC;   // later reused for gated y
    float* z     = wsp + OFF_Z;
    float* bands = wsp + OFF_BANDS;
    float* u     = wsp + OFF_U;
    float* delta = wsp + OFF_DELTA;
    float* Bs    = wsp + OFF_BS;
    float* Cs    = wsp + OFF_CS;
    float* dsum  = wsp + OFF_DSUM;
    float* hend  = wsp + OFF_HEND;
    float* hin   = wsp + OFF_HIN;
    float* h11   = wsp + OFF_H11;
    float* xd    = wsp + OFF_XDBL;
    unsigned short* wq = (unsigned short*)(wsp + OFF_WCVT);
    unsigned short* whi_in  = wq;
    unsigned short* wlo_in  = wq + 32768;
    unsigned short* whi_out = wq + 65536;
    unsigned short* wlo_out = wq + 81920;
    unsigned short* whi_xw  = wq + 98304;
    unsigned short* wlo_xw  = wq + 102400;
    float* out   = (float*)d_out;

    // 0) split weights into bf16 hi/lo
    k_cvt<<<208, 256, 0, stream>>>(in_w, out_w, x_w, wq);
    // 1) in_proj GEMM (MFMA, weights-in-regs, r4 config) -> x_proc, z
    k_gemm2<false><<<512, 256, 0, stream>>>(x, whi_in, wlo_in, xproc, z, nullptr, nullptr);
    // 2) 2-level DWT -> bands1 + compact active-region u
    k_dwt<<<512, 256, 0, stream>>>(xproc, bands, u);
    // 3a) x_dbl = u @ x_proj^T (MFMA)
    k_xdbl<<<128, 256, 0, stream>>>(u, whi_xw, wlo_xw, xd);
    // 3b) delta / Bs / Cs (fully parallel)
    k_dbc<<<8192, 256, 0, stream>>>(xd, prompt, dt_w, dt_b, delta, Bs, Cs);
    // 4) chunked scan: summaries
    k_scan1<<<512, 256, 0, stream>>>(delta, u, Bs, A_logs, dsum, hend);
    // 5) serial combine across chunk boundaries
    k_comb<<<16, 256, 0, stream>>>(dsum, hend, A_logs, dt_b, hin);
    // 6) re-scan with true initial states -> h11
    k_scan2<<<512, 256, 0, stream>>>(delta, u, Bs, Cs, A_logs, Ds, hin, h11);
    // 7) fused inverse DWT + LayerNorm + SiLU gate -> y (xproc buffer)
    k_idwt_ln<<<512, 256, 0, stream>>>(h11, bands, z, gam, bet, xproc);
    // 8) out_proj GEMM + bias + residual -> d_out
    k_gemm2<true><<<512, 256, 0, stream>>>(xproc, whi_out, wlo_out, out, nullptr, out_b, x);
}